// Round 2
// baseline (3663.837 us; speedup 1.0000x reference)
//
#include <hip/hip_runtime.h>
#include <stdint.h>

#define T_LEN 4096
#define NHID  128

typedef float    f32x4 __attribute__((ext_vector_type(4)));
typedef _Float16 f16x4 __attribute__((ext_vector_type(4)));
typedef __fp16   h16x2 __attribute__((ext_vector_type(2)));
typedef uint32_t u32x2 __attribute__((ext_vector_type(2)));
typedef uint32_t u32x4 __attribute__((ext_vector_type(4)));

struct HPair { f16x4 a, b; };
struct P2    { h16x2 lo, hi; };

static __device__ __forceinline__ f16x4 cvt_f16x4(f32x4 v) {
    P2 p;
    p.lo = __builtin_amdgcn_cvt_pkrtz(v.x, v.y);
    p.hi = __builtin_amdgcn_cvt_pkrtz(v.z, v.w);
    return __builtin_bit_cast(f16x4, p);
}
static __device__ __forceinline__ f32x4 relu4(f32x4 v) {
    v.x = fmaxf(v.x, 0.f); v.y = fmaxf(v.y, 0.f);
    v.z = fmaxf(v.z, 0.f); v.w = fmaxf(v.w, 0.f);
    return v;
}
#define MFMA16(a, b, c) __builtin_amdgcn_mfma_f32_16x16x16f16((a), (b), (c), 0, 0, 0)

// -------------------------------------------------------------------------
// Kernel 0: xp[b,t,h] = sum_i input[b,t,i] * W1x[h,i] + b1[h]
// Written into d_out (reused as scratch) in MFMA C-layout order:
//   float index = ((t*4 + g)*64 + lane)*32 + m*4 + r
//   where lane=(u<<4)|c, batch=16g+c, hidden=16m+4u+r
// Grid: 2048 blocks (g*512 + tchunk), 64 threads.
// -------------------------------------------------------------------------
__global__ __launch_bounds__(64, 2)
void xproj_kernel(const float* __restrict__ input, const float* __restrict__ W1,
                  const float* __restrict__ b1, float* __restrict__ xp) {
    const int bid = blockIdx.x;
    const int g   = bid >> 9;          // 0..3
    const int tc  = bid & 511;         // 0..511
    const int l   = threadIdx.x;
    const int c   = l & 15, u = l >> 4;

    // A-fragments of W1x (cols 128..255 of W1)
    f16x4 wa[8][8];
#pragma unroll
    for (int m = 0; m < 8; ++m) {
        const float* wr = W1 + (16 * m + c) * 256 + 128 + 4 * u;
#pragma unroll
        for (int s = 0; s < 8; ++s)
            wa[m][s] = cvt_f16x4(*(const f32x4*)(wr + 16 * s));
    }
    f32x4 bi[8];
#pragma unroll
    for (int m = 0; m < 8; ++m) bi[m] = *(const f32x4*)(b1 + 16 * m + 4 * u);

    const int t0 = tc * 8;
    const float* ip0 = input + (size_t)(16 * g + c) * T_LEN * NHID + 4 * u;
#pragma unroll 1
    for (int tt = 0; tt < 8; ++tt) {
        const int t = t0 + tt;
        const float* ip = ip0 + (size_t)t * NHID;
        f16x4 xb[8];
#pragma unroll
        for (int s = 0; s < 8; ++s) xb[s] = cvt_f16x4(*(const f32x4*)(ip + 16 * s));
        f32x4 acc[8];
#pragma unroll
        for (int m = 0; m < 8; ++m) {
            f32x4 a = bi[m];
#pragma unroll
            for (int s = 0; s < 8; ++s) a = MFMA16(wa[m][s], xb[s], a);
            acc[m] = a;
        }
        f32x4* op = (f32x4*)(xp + ((size_t)(t * 4 + g) * 64 + l) * 32);
#pragma unroll
        for (int m = 0; m < 8; ++m) op[m] = acc[m];
    }
}

// -------------------------------------------------------------------------
// Kernel 1: the sequential recurrence. 4 blocks x 64 threads (1 wave each).
// h_{t+1} = relu(W1h . h_t + xp_t), stored as packed f16 (B-frag layout):
//   dword index = ((t*4 + g)*64 + lane)*16 + m*2 + {0,1}
// C-layout of 16x16x16 == B-layout -> no cross-lane exchange needed.
// -------------------------------------------------------------------------
__global__ __launch_bounds__(64, 1)
void rec_kernel(const float* __restrict__ xp, const float* __restrict__ W1,
                uint32_t* __restrict__ hws) {
    const int g = blockIdx.x;
    const int l = threadIdx.x;
    const int c = l & 15, u = l >> 4;

    // A-fragments of W1h (cols 0..127 of W1)
    f16x4 wa[8][8];
#pragma unroll
    for (int m = 0; m < 8; ++m) {
        const float* wr = W1 + (16 * m + c) * 256 + 4 * u;
#pragma unroll
        for (int s = 0; s < 8; ++s)
            wa[m][s] = cvt_f16x4(*(const f32x4*)(wr + 16 * s));
    }

    f16x4 hf[8];
#pragma unroll
    for (int s = 0; s < 8; ++s) hf[s] = (f16x4)0;

    const f32x4* xpp = (const f32x4*)xp + ((size_t)g * 64 + l) * 8;  // +2048 per t
    uint32_t*    hp  = hws + ((size_t)g * 64 + l) * 16;              // +4096 per t

    // register prefetch pipeline, depth 4
    f32x4 xb[4][8];
#pragma unroll
    for (int p = 0; p < 4; ++p)
#pragma unroll
        for (int m = 0; m < 8; ++m) xb[p][m] = xpp[(size_t)p * 2048 + m];

#pragma unroll 1
    for (int t4 = 0; t4 < T_LEN; t4 += 4) {
#pragma unroll
        for (int p = 0; p < 4; ++p) {
            const int t = t4 + p;
            f32x4 acc[8];
#pragma unroll
            for (int m = 0; m < 8; ++m) {
                f32x4 a = xb[p][m];
#pragma unroll
                for (int s = 0; s < 8; ++s) a = MFMA16(wa[m][s], hf[s], a);
                acc[m] = a;
            }
            // prefetch xp for t+4 (clamped; last loads are dummies)
            int tn = t + 4; if (tn > T_LEN - 1) tn = T_LEN - 1;
            const f32x4* pf = xpp + (size_t)tn * 2048;
#pragma unroll
            for (int m = 0; m < 8; ++m) xb[p][m] = pf[m];
            // relu + convert -> new h fragments (in place, in lane)
#pragma unroll
            for (int m = 0; m < 8; ++m) hf[m] = cvt_f16x4(relu4(acc[m]));
            // store h_{t+1} for the output projection kernel
            uint32_t* ho = hp + (size_t)t * 4096;
#pragma unroll
            for (int m = 0; m < 8; ++m)
                *(u32x2*)(ho + 2 * m) = __builtin_bit_cast(u32x2, hf[m]);
        }
    }
}

// -------------------------------------------------------------------------
// Kernel 2: out[b,t,h] = relu(sum_k W2[h,k] * h[b,t,k] + b2[h])
// h fragments are read verbatim (already in B-frag layout).
// Grid: 2048 blocks (g*512 + tchunk), 64 threads.
// -------------------------------------------------------------------------
__global__ __launch_bounds__(64, 2)
void out_kernel(const uint32_t* __restrict__ hws, const float* __restrict__ W2,
                const float* __restrict__ b2, float* __restrict__ out) {
    const int bid = blockIdx.x;
    const int g   = bid >> 9;
    const int tc  = bid & 511;
    const int l   = threadIdx.x;
    const int c   = l & 15, u = l >> 4;

    f16x4 wa[8][8];
#pragma unroll
    for (int m = 0; m < 8; ++m) {
        const float* wr = W2 + (16 * m + c) * 128 + 4 * u;
#pragma unroll
        for (int s = 0; s < 8; ++s)
            wa[m][s] = cvt_f16x4(*(const f32x4*)(wr + 16 * s));
    }
    f32x4 bi[8];
#pragma unroll
    for (int m = 0; m < 8; ++m) bi[m] = *(const f32x4*)(b2 + 16 * m + 4 * u);

    const int t0 = tc * 8;
    float* op0 = out + (size_t)(16 * g + c) * T_LEN * NHID + 4 * u;
#pragma unroll 1
    for (int tt = 0; tt < 8; ++tt) {
        const int t = t0 + tt;
        const uint32_t* hpt = hws + ((size_t)(t * 4 + g) * 64 + l) * 16;
        f16x4 hb[8];
#pragma unroll
        for (int i = 0; i < 4; ++i) {
            u32x4 q = *(const u32x4*)(hpt + 4 * i);
            HPair hpair = __builtin_bit_cast(HPair, q);
            hb[2 * i]     = hpair.a;
            hb[2 * i + 1] = hpair.b;
        }
        f32x4 acc[8];
#pragma unroll
        for (int m = 0; m < 8; ++m) {
            f32x4 a = bi[m];
#pragma unroll
            for (int s = 0; s < 8; ++s) a = MFMA16(wa[m][s], hb[s], a);
            acc[m] = relu4(a);
        }
        float* op = op0 + (size_t)t * NHID;
#pragma unroll
        for (int m = 0; m < 8; ++m) *(f32x4*)(op + 16 * m) = acc[m];
    }
}

// -------------------------------------------------------------------------
extern "C" void kernel_launch(void* const* d_in, const int* in_sizes, int n_in,
                              void* d_out, int out_size, void* d_ws, size_t ws_size,
                              hipStream_t stream) {
    const float* input = (const float*)d_in[0];  // (64, 4096, 128) f32
    const float* W1    = (const float*)d_in[1];  // (128, 256) f32
    const float* b1    = (const float*)d_in[2];  // (128,) f32
    const float* W2    = (const float*)d_in[3];  // (128, 128) f32
    const float* b2    = (const float*)d_in[4];  // (128,) f32
    float*    out = (float*)d_out;
    uint32_t* hws = (uint32_t*)d_ws;             // needs 4096*4*64*16*4 = 64 MiB
    float*    xpb = out;                          // reuse d_out as xp scratch
                                                  // (k2 overwrites it afterwards)

    xproj_kernel<<<2048, 64, 0, stream>>>(input, W1, b1, xpb);
    rec_kernel  <<<4,    64, 0, stream>>>(xpb, W1, hws);
    out_kernel  <<<2048, 64, 0, stream>>>(hws, W2, b2, out);
}

// Round 3
// 1834.819 us; speedup vs baseline: 1.9968x; 1.9968x over previous
//
#include <hip/hip_runtime.h>
#include <stdint.h>

#define T_LEN 4096
#define NHID  128

typedef float    f32x4 __attribute__((ext_vector_type(4)));
typedef _Float16 f16x4 __attribute__((ext_vector_type(4)));
typedef __fp16   h16x2 __attribute__((ext_vector_type(2)));
typedef uint32_t u32x2 __attribute__((ext_vector_type(2)));

struct P2 { h16x2 lo, hi; };

static __device__ __forceinline__ f16x4 cvt_f16x4(f32x4 v) {
    P2 p;
    p.lo = __builtin_amdgcn_cvt_pkrtz(v.x, v.y);
    p.hi = __builtin_amdgcn_cvt_pkrtz(v.z, v.w);
    return __builtin_bit_cast(f16x4, p);
}
static __device__ __forceinline__ f32x4 relu4(f32x4 v) {
    v.x = fmaxf(v.x, 0.f); v.y = fmaxf(v.y, 0.f);
    v.z = fmaxf(v.z, 0.f); v.w = fmaxf(v.w, 0.f);
    return v;
}
#define MFMA16(a, b, c) __builtin_amdgcn_mfma_f32_16x16x16f16((a), (b), (c), 0, 0, 0)

// CK-style barrier: order LDS only (lgkmcnt), leave global loads in flight.
#define LDS_BARRIER() asm volatile("s_waitcnt lgkmcnt(0)\n\ts_barrier" ::: "memory")

// -------------------------------------------------------------------------
// Kernel 0: xp[b,t,h] = sum_i input[b,t,i]*W1x[h,i] + b1[h], packed f16.
// Layout (dwords): ((m*4 + g)*4096 + t)*128 + 2*lane + {0,1}
//   lane=(u<<4)|c : batch=16g+c, hidden=16m+4u+{0..3} (MFMA C-frag order).
// Per-wave stream for rec is contiguous; all stores coalesced.
// -------------------------------------------------------------------------
__global__ __launch_bounds__(64, 2)
void xproj_kernel(const float* __restrict__ input, const float* __restrict__ W1,
                  const float* __restrict__ b1, uint32_t* __restrict__ xp) {
    const int bid = blockIdx.x;
    const int g   = bid >> 9;          // 0..3
    const int tc  = bid & 511;         // 0..511
    const int l   = threadIdx.x;
    const int c   = l & 15, u = l >> 4;

    // A-fragments of W1x (cols 128..255 of W1)
    f16x4 wa[8][8];
#pragma unroll
    for (int m = 0; m < 8; ++m) {
        const float* wr = W1 + (16 * m + c) * 256 + 128 + 4 * u;
#pragma unroll
        for (int s = 0; s < 8; ++s)
            wa[m][s] = cvt_f16x4(*(const f32x4*)(wr + 16 * s));
    }
    f32x4 bi[8];
#pragma unroll
    for (int m = 0; m < 8; ++m) bi[m] = *(const f32x4*)(b1 + 16 * m + 4 * u);

    const int t0 = tc * 8;
    const float* ip0 = input + (size_t)(16 * g + c) * T_LEN * NHID + 4 * u;
#pragma unroll 1
    for (int tt = 0; tt < 8; ++tt) {
        const int t = t0 + tt;
        const float* ip = ip0 + (size_t)t * NHID;
        f16x4 xb[8];
#pragma unroll
        for (int s = 0; s < 8; ++s) xb[s] = cvt_f16x4(*(const f32x4*)(ip + 16 * s));
#pragma unroll
        for (int m = 0; m < 8; ++m) {
            f32x4 a = bi[m];
#pragma unroll
            for (int s = 0; s < 8; ++s) a = MFMA16(wa[m][s], xb[s], a);
            u32x2 pk = __builtin_bit_cast(u32x2, cvt_f16x4(a));
            *(u32x2*)(xp + ((size_t)(m * 4 + g) * T_LEN + t) * 128 + 2 * l) = pk;
        }
    }
}

// -------------------------------------------------------------------------
// Kernel 1: fused recurrence + output projection.
// Grid 4 (g = batch group of 16), block 512 = 8 waves; wave w owns hidden
// tile m=w (16 rows). Per step:
//   read full h_t (8 tiles) from LDS buf[t&1]      (B-frag layout)
//   h_{t+1}^w = relu(W1h^w . h_t + xp_t^w)  -> write to buf[(t&1)^1]
//   out_{t-1} = relu(W2^w . h_t + b2)       -> store f32 to d_out
//   prefetch xp_{t+8};  lgkm-only barrier.
// C-layout == B-layout (16x16x16) -> no repacking anywhere.
// -------------------------------------------------------------------------
__global__ __launch_bounds__(512)
void rec_kernel(const uint32_t* __restrict__ xp, const float* __restrict__ W1,
                const float* __restrict__ W2, const float* __restrict__ b2,
                float* __restrict__ out) {
    const int g = blockIdx.x;
    const int w = threadIdx.x >> 6;
    const int l = threadIdx.x & 63;
    const int c = l & 15, u = l >> 4;

    __shared__ uint32_t lds[2][8][128];   // [buf][tile][2*lane+j], 8 KB

    // A-fragments: W1h (cols 0..127) rows 16w..16w+15; W2 rows 16w..16w+15
    f16x4 wa[8], w2a[8];
#pragma unroll
    for (int s = 0; s < 8; ++s) {
        wa[s]  = cvt_f16x4(*(const f32x4*)(W1 + (16 * w + c) * 256 + 16 * s + 4 * u));
        w2a[s] = cvt_f16x4(*(const f32x4*)(W2 + (16 * w + c) * 128 + 16 * s + 4 * u));
    }
    const f32x4 bi = *(const f32x4*)(b2 + 16 * w + 4 * u);

    // h_0 = 0
    *(u32x2*)&lds[0][w][2 * l] = (u32x2)0;
    __syncthreads();

    const uint32_t* xpu = xp + ((size_t)(w * 4 + g) * T_LEN) * 128 + 2 * l;
    float* outp = out + (size_t)(16 * g + c) * T_LEN * NHID + 16 * w + 4 * u;

    // xp prefetch ring, depth 8
    u32x2 xb[8];
#pragma unroll
    for (int p = 0; p < 8; ++p) xb[p] = *(const u32x2*)(xpu + (size_t)p * 128);

#pragma unroll 1
    for (int t8 = 0; t8 < T_LEN; t8 += 8) {
#pragma unroll
        for (int p = 0; p < 8; ++p) {
            const int t   = t8 + p;
            const int cur = p & 1;        // t8 is even, so t&1 == p&1

            // read full h_t (B-fragments); 2-way bank alias = free
            f16x4 hb[8];
#pragma unroll
            for (int s = 0; s < 8; ++s)
                hb[s] = __builtin_bit_cast(f16x4, *(const u32x2*)&lds[cur][s][2 * l]);

            // h update: two independent chains of 4
            f16x4 xf = __builtin_bit_cast(f16x4, xb[p]);
            f32x4 acc0 = { (float)xf.x, (float)xf.y, (float)xf.z, (float)xf.w };
            f32x4 acc1 = { 0.f, 0.f, 0.f, 0.f };
#pragma unroll
            for (int s = 0; s < 4; ++s) acc0 = MFMA16(wa[s], hb[s], acc0);
#pragma unroll
            for (int s = 4; s < 8; ++s) acc1 = MFMA16(wa[s], hb[s], acc1);

            // out_{t-1} = relu(W2 . h_t + b2)   (off the critical path)
            f32x4 oacc = bi;
#pragma unroll
            for (int s = 0; s < 8; ++s) oacc = MFMA16(w2a[s], hb[s], oacc);

            f16x4 hf = cvt_f16x4(relu4(acc0 + acc1));
            *(u32x2*)&lds[cur ^ 1][w][2 * l] = __builtin_bit_cast(u32x2, hf);

            if (t != 0)
                *(f32x4*)(outp + (size_t)(t - 1) * NHID) = relu4(oacc);

            // prefetch xp for t+8 (clamped; tail loads are dummies)
            int tn = t + 8; if (tn > T_LEN - 1) tn = T_LEN - 1;
            xb[p] = *(const u32x2*)(xpu + (size_t)tn * 128);

            LDS_BARRIER();
        }
    }

    // epilogue: out_{T-1} = relu(W2 . h_T + b2); h_T is in buf[0]
    {
        f32x4 oacc = bi;
#pragma unroll
        for (int s = 0; s < 8; ++s) {
            f16x4 hb = __builtin_bit_cast(f16x4, *(const u32x2*)&lds[0][s][2 * l]);
            oacc = MFMA16(w2a[s], hb, oacc);
        }
        *(f32x4*)(outp + (size_t)(T_LEN - 1) * NHID) = relu4(oacc);
    }
}

// -------------------------------------------------------------------------
extern "C" void kernel_launch(void* const* d_in, const int* in_sizes, int n_in,
                              void* d_out, int out_size, void* d_ws, size_t ws_size,
                              hipStream_t stream) {
    const float* input = (const float*)d_in[0];  // (64, 4096, 128) f32
    const float* W1    = (const float*)d_in[1];  // (128, 256) f32
    const float* b1    = (const float*)d_in[2];  // (128,) f32
    const float* W2    = (const float*)d_in[3];  // (128, 128) f32
    const float* b2    = (const float*)d_in[4];  // (128,) f32
    float*    out = (float*)d_out;
    uint32_t* xpb = (uint32_t*)d_ws;             // packed-f16 xp, 64 MiB

    xproj_kernel<<<2048, 64, 0, stream>>>(input, W1, b1, xpb);
    rec_kernel  <<<4,   512, 0, stream>>>(xpb, W1, W2, b2, out);
}

// Round 4
// 1499.103 us; speedup vs baseline: 2.4440x; 1.2239x over previous
//
#include <hip/hip_runtime.h>
#include <stdint.h>

#define T_LEN 4096
#define NHID  128

typedef float    f32x4 __attribute__((ext_vector_type(4)));
typedef _Float16 f16x4 __attribute__((ext_vector_type(4)));
typedef _Float16 f16x8 __attribute__((ext_vector_type(8)));
typedef __fp16   h16x2 __attribute__((ext_vector_type(2)));
typedef uint32_t u32x2 __attribute__((ext_vector_type(2)));

struct P2 { h16x2 p0, p1; };
struct P4 { h16x2 p0, p1, p2, p3; };

static __device__ __forceinline__ f16x4 cvt_f16x4(f32x4 v) {
    P2 p;
    p.p0 = __builtin_amdgcn_cvt_pkrtz(v.x, v.y);
    p.p1 = __builtin_amdgcn_cvt_pkrtz(v.z, v.w);
    return __builtin_bit_cast(f16x4, p);
}
static __device__ __forceinline__ f16x8 cvt_f16x8(f32x4 a, f32x4 b) {
    P4 p;
    p.p0 = __builtin_amdgcn_cvt_pkrtz(a.x, a.y);
    p.p1 = __builtin_amdgcn_cvt_pkrtz(a.z, a.w);
    p.p2 = __builtin_amdgcn_cvt_pkrtz(b.x, b.y);
    p.p3 = __builtin_amdgcn_cvt_pkrtz(b.z, b.w);
    return __builtin_bit_cast(f16x8, p);
}
static __device__ __forceinline__ f32x4 relu4(f32x4 v) {
    v.x = fmaxf(v.x, 0.f); v.y = fmaxf(v.y, 0.f);
    v.z = fmaxf(v.z, 0.f); v.w = fmaxf(v.w, 0.f);
    return v;
}
#define MFMA32(a, b, c) __builtin_amdgcn_mfma_f32_16x16x32_f16((a), (b), (c), 0, 0, 0)

// CK-style barrier: order LDS only (lgkmcnt), leave global loads in flight.
#define LDS_BARRIER() asm volatile("s_waitcnt lgkmcnt(0)\n\ts_barrier" ::: "memory")

// -------------------------------------------------------------------------
// Kernel 0: xp[b,t,h] = sum_i input[b,t,i]*W1x[h,i] + b1[h], packed f16.
// Layout (dwords): ((m*4 + g)*4096 + t)*128 + 2*lane + {0,1}
//   lane=(u<<4)|c : batch=16g+c, hidden=16m+4u+{0..3} (MFMA C-frag order).
// K=32 MFMA; 16 t per block; grid 1024 x 64.
// -------------------------------------------------------------------------
__global__ __launch_bounds__(64, 2)
void xproj_kernel(const float* __restrict__ input, const float* __restrict__ W1,
                  const float* __restrict__ b1, uint32_t* __restrict__ xp) {
    const int bid = blockIdx.x;
    const int g   = bid >> 8;          // 0..3
    const int tc  = bid & 255;         // 0..255
    const int l   = threadIdx.x;
    const int c   = l & 15, u = l >> 4;

    // A-fragments of W1x (cols 128..255 of W1): A[m=c][k=32j+8u+0..7]
    f16x8 wa[8][4];
#pragma unroll
    for (int m = 0; m < 8; ++m) {
        const float* wr = W1 + (16 * m + c) * 256 + 128 + 8 * u;
#pragma unroll
        for (int j = 0; j < 4; ++j)
            wa[m][j] = cvt_f16x8(*(const f32x4*)(wr + 32 * j),
                                 *(const f32x4*)(wr + 32 * j + 4));
    }
    f32x4 bi[8];
#pragma unroll
    for (int m = 0; m < 8; ++m) bi[m] = *(const f32x4*)(b1 + 16 * m + 4 * u);

    const int t0 = tc * 16;
    const float* ip0 = input + (size_t)(16 * g + c) * T_LEN * NHID + 8 * u;
#pragma unroll 1
    for (int tt = 0; tt < 16; ++tt) {
        const int t = t0 + tt;
        const float* ip = ip0 + (size_t)t * NHID;
        // B-fragments of x: B[k=32j+8u+0..7][n=c]
        f16x8 xb[4];
#pragma unroll
        for (int j = 0; j < 4; ++j)
            xb[j] = cvt_f16x8(*(const f32x4*)(ip + 32 * j),
                              *(const f32x4*)(ip + 32 * j + 4));
#pragma unroll
        for (int m = 0; m < 8; ++m) {
            f32x4 a = bi[m];
#pragma unroll
            for (int j = 0; j < 4; ++j) a = MFMA32(wa[m][j], xb[j], a);
            u32x2 pk = __builtin_bit_cast(u32x2, cvt_f16x4(a));
            *(u32x2*)(xp + ((size_t)(m * 4 + g) * T_LEN + t) * 128 + 2 * l) = pk;
        }
    }
}

// -------------------------------------------------------------------------
// Kernel 1: fused recurrence + output projection, K=32 MFMA.
// Grid 4 (g = batch group of 16), block 512 = 8 waves; wave w owns hidden
// rows [16w, 16w+16). LDS h layout: h16[batch][hidden], row padded to 136
// f16 (272 B) -> bank base 4c mod 32: 2-way aliasing only (free).
//   writer (C-frag): lane(u,c) -> hlds[buf][c][16w+4u .. +4]   (b64)
//   reader (B-frag): lane(u,c), MFMA j -> hlds[buf][c][32j+8u .. +8] (b128)
// -------------------------------------------------------------------------
__global__ __launch_bounds__(512)
void rec_kernel(const uint32_t* __restrict__ xp, const float* __restrict__ W1,
                const float* __restrict__ W2, const float* __restrict__ b2,
                float* __restrict__ out) {
    const int g = blockIdx.x;
    const int w = threadIdx.x >> 6;
    const int l = threadIdx.x & 63;
    const int c = l & 15, u = l >> 4;

    __shared__ _Float16 hlds[2][16][136];   // 8704 B

    // A-fragments: W1h rows 16w.., cols 0..127; W2 rows 16w..
    f16x8 wa[4], w2a[4];
#pragma unroll
    for (int j = 0; j < 4; ++j) {
        const float* w1r = W1 + (16 * w + c) * 256 + 32 * j + 8 * u;
        const float* w2r = W2 + (16 * w + c) * 128 + 32 * j + 8 * u;
        wa[j]  = cvt_f16x8(*(const f32x4*)(w1r), *(const f32x4*)(w1r + 4));
        w2a[j] = cvt_f16x8(*(const f32x4*)(w2r), *(const f32x4*)(w2r + 4));
    }
    const f32x4 bi = *(const f32x4*)(b2 + 16 * w + 4 * u);

    // h_0 = 0 (zero both buffers)
    {
        uint32_t* z = (uint32_t*)&hlds[0][0][0];
        for (int i = threadIdx.x; i < 2176; i += 512) z[i] = 0;
    }
    __syncthreads();

    const uint32_t* xpu = xp + ((size_t)(w * 4 + g) * T_LEN) * 128 + 2 * l;
    float* outp = out + (size_t)(16 * g + c) * T_LEN * NHID + 16 * w + 4 * u;

    // xp prefetch ring, depth 8
    u32x2 xb[8];
#pragma unroll
    for (int p = 0; p < 8; ++p) xb[p] = *(const u32x2*)(xpu + (size_t)p * 128);

#pragma unroll 1
    for (int t8 = 0; t8 < T_LEN; t8 += 8) {
#pragma unroll
        for (int p = 0; p < 8; ++p) {
            const int t   = t8 + p;
            const int cur = p & 1;        // t8 even -> t&1 == p&1

            // read h_t B-fragments (4 x b128, 2-way aliasing)
            f16x8 hb[4];
#pragma unroll
            for (int j = 0; j < 4; ++j)
                hb[j] = *(const f16x8*)&hlds[cur][c][32 * j + 8 * u];

            // h update: two independent chains of 2
            f16x4 xf = __builtin_bit_cast(f16x4, xb[p]);
            f32x4 acc0 = { (float)xf.x, (float)xf.y, (float)xf.z, (float)xf.w };
            f32x4 acc1 = { 0.f, 0.f, 0.f, 0.f };
            acc0 = MFMA32(wa[0], hb[0], acc0);
            acc1 = MFMA32(wa[1], hb[1], acc1);
            acc0 = MFMA32(wa[2], hb[2], acc0);
            acc1 = MFMA32(wa[3], hb[3], acc1);

            f16x4 hf = cvt_f16x4(relu4(acc0 + acc1));
            *(u32x2*)&hlds[cur ^ 1][c][16 * w + 4 * u] =
                __builtin_bit_cast(u32x2, hf);

            // out_{t-1} = relu(W2 . h_t + b2)  (off the critical path)
            f32x4 oacc = bi;
#pragma unroll
            for (int j = 0; j < 4; ++j) oacc = MFMA32(w2a[j], hb[j], oacc);
            if (t != 0)
                *(f32x4*)(outp + (size_t)(t - 1) * NHID) = relu4(oacc);

            // prefetch xp for t+8 (clamped; tail loads are dummies)
            int tn = t + 8; if (tn > T_LEN - 1) tn = T_LEN - 1;
            xb[p] = *(const u32x2*)(xpu + (size_t)tn * 128);

            LDS_BARRIER();
        }
    }

    // epilogue: out_{T-1} = relu(W2 . h_T + b2); h_T is in buf[0]
    {
        f32x4 oacc = bi;
#pragma unroll
        for (int j = 0; j < 4; ++j) {
            f16x8 hb = *(const f16x8*)&hlds[0][c][32 * j + 8 * u];
            oacc = MFMA32(w2a[j], hb, oacc);
        }
        *(f32x4*)(outp + (size_t)(T_LEN - 1) * NHID) = relu4(oacc);
    }
}

// -------------------------------------------------------------------------
extern "C" void kernel_launch(void* const* d_in, const int* in_sizes, int n_in,
                              void* d_out, int out_size, void* d_ws, size_t ws_size,
                              hipStream_t stream) {
    const float* input = (const float*)d_in[0];  // (64, 4096, 128) f32
    const float* W1    = (const float*)d_in[1];  // (128, 256) f32
    const float* b1    = (const float*)d_in[2];  // (128,) f32
    const float* W2    = (const float*)d_in[3];  // (128, 128) f32
    const float* b2    = (const float*)d_in[4];  // (128,) f32
    float*    out = (float*)d_out;
    uint32_t* xpb = (uint32_t*)d_ws;             // packed-f16 xp, 64 MiB

    xproj_kernel<<<1024, 64, 0, stream>>>(input, W1, b1, xpb);
    rec_kernel  <<<4,   512, 0, stream>>>(xpb, W1, W2, b2, out);
}

// Round 5
// 1410.503 us; speedup vs baseline: 2.5975x; 1.0628x over previous
//
#include <hip/hip_runtime.h>
#include <stdint.h>

#define T_LEN 4096
#define NHID  128

typedef float    f32x4 __attribute__((ext_vector_type(4)));
typedef _Float16 f16x4 __attribute__((ext_vector_type(4)));
typedef _Float16 f16x8 __attribute__((ext_vector_type(8)));
typedef __fp16   h16x2 __attribute__((ext_vector_type(2)));
typedef uint32_t u32x2 __attribute__((ext_vector_type(2)));
typedef uint32_t u32x4 __attribute__((ext_vector_type(4)));

struct P2 { h16x2 p0, p1; };
struct P4 { h16x2 p0, p1, p2, p3; };
struct U22 { u32x2 a, b; };

static __device__ __forceinline__ f16x4 cvt_f16x4(f32x4 v) {
    P2 p;
    p.p0 = __builtin_amdgcn_cvt_pkrtz(v.x, v.y);
    p.p1 = __builtin_amdgcn_cvt_pkrtz(v.z, v.w);
    return __builtin_bit_cast(f16x4, p);
}
static __device__ __forceinline__ f16x8 cvt_f16x8(f32x4 a, f32x4 b) {
    P4 p;
    p.p0 = __builtin_amdgcn_cvt_pkrtz(a.x, a.y);
    p.p1 = __builtin_amdgcn_cvt_pkrtz(a.z, a.w);
    p.p2 = __builtin_amdgcn_cvt_pkrtz(b.x, b.y);
    p.p3 = __builtin_amdgcn_cvt_pkrtz(b.z, b.w);
    return __builtin_bit_cast(f16x8, p);
}
static __device__ __forceinline__ f32x4 relu4(f32x4 v) {
    v.x = fmaxf(v.x, 0.f); v.y = fmaxf(v.y, 0.f);
    v.z = fmaxf(v.z, 0.f); v.w = fmaxf(v.w, 0.f);
    return v;
}
#define MFMA32(a, b, c) __builtin_amdgcn_mfma_f32_16x16x32_f16((a), (b), (c), 0, 0, 0)
#define MFMA16(a, b, c) __builtin_amdgcn_mfma_f32_16x16x16f16((a), (b), (c), 0, 0, 0)

// LDS-only barrier: leave global (vmcnt) traffic in flight.
#define LDS_BARRIER() asm volatile("s_waitcnt lgkmcnt(0)\n\ts_barrier" ::: "memory")

// Shared f16 fragment layout for xp and h (per batch-group g, per step t):
//   dword index = (((w*4 + g)*T_LEN + t)*64 + lane)*4 + e*2 + d
//   lane=(u<<4)|c : batch=16g+c, hidden H=16*(2w+e)+4u+{2d,2d+1} (C-frag order)
// One dwordx4 per lane per step: fully coalesced (1 KB per wave).

// -------------------------------------------------------------------------
// Kernel 0: xp = input . W1x^T + b1  (K=32 MFMA), packed f16, layout above.
// Grid 1024 = g*256 + tc, block 64, 16 t per block.
// -------------------------------------------------------------------------
__global__ __launch_bounds__(64, 2)
void xproj_kernel(const float* __restrict__ input, const float* __restrict__ W1,
                  const float* __restrict__ b1, uint32_t* __restrict__ xp) {
    const int bid = blockIdx.x;
    const int g   = bid >> 8;          // 0..3
    const int tc  = bid & 255;         // 0..255
    const int l   = threadIdx.x;
    const int c   = l & 15, u = l >> 4;

    // A-fragments of W1x (cols 128..255): A[m=c][k=32j+8u+0..7]
    f16x8 wa[8][4];
#pragma unroll
    for (int m = 0; m < 8; ++m) {
        const float* wr = W1 + (16 * m + c) * 256 + 128 + 8 * u;
#pragma unroll
        for (int j = 0; j < 4; ++j)
            wa[m][j] = cvt_f16x8(*(const f32x4*)(wr + 32 * j),
                                 *(const f32x4*)(wr + 32 * j + 4));
    }
    f32x4 bi[8];
#pragma unroll
    for (int m = 0; m < 8; ++m) bi[m] = *(const f32x4*)(b1 + 16 * m + 4 * u);

    const int t0 = tc * 16;
    const float* ip0 = input + (size_t)(16 * g + c) * T_LEN * NHID + 8 * u;
#pragma unroll 1
    for (int tt = 0; tt < 16; ++tt) {
        const int t = t0 + tt;
        const float* ip = ip0 + (size_t)t * NHID;
        f16x8 xb[4];
#pragma unroll
        for (int j = 0; j < 4; ++j)
            xb[j] = cvt_f16x8(*(const f32x4*)(ip + 32 * j),
                              *(const f32x4*)(ip + 32 * j + 4));
        u32x2 pk[8];
#pragma unroll
        for (int m = 0; m < 8; ++m) {
            f32x4 a = bi[m];
#pragma unroll
            for (int j = 0; j < 4; ++j) a = MFMA32(wa[m][j], xb[j], a);
            pk[m] = __builtin_bit_cast(u32x2, cvt_f16x4(a));
        }
#pragma unroll
        for (int w = 0; w < 4; ++w) {
            U22 q2 = { pk[2 * w], pk[2 * w + 1] };
            u32x4 q = __builtin_bit_cast(u32x4, q2);
            *(u32x4*)(xp + (((size_t)(w * 4 + g) * T_LEN + t) * 64 + l) * 4) = q;
        }
    }
}

// -------------------------------------------------------------------------
// Kernel 1: recurrence only. Grid 4 (g), block 256 = 4 waves.
// Wave w owns hidden rows [32w, 32w+32) = m-tiles {2w, 2w+1}.
// LDS h layout (plane-split fragment order), per parity buffer:
//   harr[buf][ j*256 + p*128 + 2*((u'<<4)|c) + d ]
//   holds h16 for batch c, hidden 32j + 8u' + 4p + {2d, 2d+1}
// Reads  (lane l, frag j): b64 at [j*256 + 2l] and [j*256+128 + 2l]
//        -> banks 2l mod 32, uniform 4/bank-pair (round-3-proven, 0 confl).
// Writes (wave w == j): for e=0,1: b64 at [w*256 + (u&1)*128 + 2*((u''<<4)|c)]
//        u'' = 2e + (u>>1)  -> banks 2c mod 32, uniform 4/bank-pair.
// h is also streamed to HBM (dwordx4, fire-and-forget) for out_kernel.
// -------------------------------------------------------------------------
__global__ __launch_bounds__(256, 1)
void rec_kernel(const uint32_t* __restrict__ xp, const float* __restrict__ W1,
                uint32_t* __restrict__ hg) {
    const int g = blockIdx.x;
    const int w = threadIdx.x >> 6;
    const int l = threadIdx.x & 63;
    const int c = l & 15, u = l >> 4;

    __shared__ uint32_t harr[2][1024];   // 8 KB

    // A-fragments of W1h: m-tile 2w+e, rows 16*(2w+e)+c, k = 32j+8u+0..7
    f16x8 wa[2][4];
#pragma unroll
    for (int e = 0; e < 2; ++e) {
        const float* wr = W1 + (16 * (2 * w + e) + c) * 256 + 8 * u;
#pragma unroll
        for (int j = 0; j < 4; ++j)
            wa[e][j] = cvt_f16x8(*(const f32x4*)(wr + 32 * j),
                                 *(const f32x4*)(wr + 32 * j + 4));
    }

    // zero both h buffers (h_0 = 0)
#pragma unroll
    for (int i = threadIdx.x; i < 2048; i += 256) harr[0][i] = 0;  // [2][1024] flat
    __syncthreads();

    const uint32_t* xpu = xp + (size_t)(w * 4 + g) * T_LEN * 256 + 4 * l;
    uint32_t*       hgp = hg + (size_t)(w * 4 + g) * T_LEN * 256 + 4 * l;

    const int wbase0 = w * 256 + ((u & 1) << 7) + 2 * ((((u >> 1)) << 4) | c);     // e=0
    const int wbase1 = w * 256 + ((u & 1) << 7) + 2 * (((2 + (u >> 1)) << 4) | c); // e=1

    // xp prefetch ring, depth 8
    u32x4 xb[8];
#pragma unroll
    for (int p = 0; p < 8; ++p) xb[p] = *(const u32x4*)(xpu + (size_t)p * 256);

#pragma unroll 1
    for (int t8 = 0; t8 < T_LEN; t8 += 8) {
#pragma unroll
        for (int p = 0; p < 8; ++p) {
            const int t   = t8 + p;
            const int cur = p & 1;     // t8 even -> t&1 == p&1

            // read full h_t: 4 frags x 2 planes, b64 each, banks 2l
            f16x8 hb[4];
#pragma unroll
            for (int j = 0; j < 4; ++j) {
                U22 q;
                q.a = *(const u32x2*)&harr[cur][j * 256 + 2 * l];
                q.b = *(const u32x2*)&harr[cur][j * 256 + 128 + 2 * l];
                hb[j] = __builtin_bit_cast(f16x8, q);
            }

            // unpack xp accumulator init (packed f16 -> f32)
            U22 xq = __builtin_bit_cast(U22, xb[p]);
            f16x4 x0 = __builtin_bit_cast(f16x4, xq.a);
            f16x4 x1 = __builtin_bit_cast(f16x4, xq.b);

            // 4 independent chains of 2 dependent MFMAs
            f32x4 a00 = { (float)x0.x, (float)x0.y, (float)x0.z, (float)x0.w };
            f32x4 a10 = { (float)x1.x, (float)x1.y, (float)x1.z, (float)x1.w };
            f32x4 a01 = { 0.f, 0.f, 0.f, 0.f };
            f32x4 a11 = { 0.f, 0.f, 0.f, 0.f };
            a00 = MFMA32(wa[0][0], hb[0], a00);
            a01 = MFMA32(wa[0][1], hb[1], a01);
            a10 = MFMA32(wa[1][0], hb[0], a10);
            a11 = MFMA32(wa[1][1], hb[1], a11);
            a00 = MFMA32(wa[0][2], hb[2], a00);
            a01 = MFMA32(wa[0][3], hb[3], a01);
            a10 = MFMA32(wa[1][2], hb[2], a10);
            a11 = MFMA32(wa[1][3], hb[3], a11);

            f16x4 hf0 = cvt_f16x4(relu4(a00 + a01));
            f16x4 hf1 = cvt_f16x4(relu4(a10 + a11));

            // write h_{t+1} fragments to LDS (banks 2c, uniform)
            *(u32x2*)&harr[cur ^ 1][wbase0] = __builtin_bit_cast(u32x2, hf0);
            *(u32x2*)&harr[cur ^ 1][wbase1] = __builtin_bit_cast(u32x2, hf1);

            // stream h_{t+1} to HBM for out_kernel (not waited on)
            U22 hq2 = { __builtin_bit_cast(u32x2, hf0), __builtin_bit_cast(u32x2, hf1) };
            *(u32x4*)(hgp + (size_t)t * 256) = __builtin_bit_cast(u32x4, hq2);

            // prefetch xp for t+8 (clamped; tail loads are dummies)
            int tn = t + 8; if (tn > T_LEN - 1) tn = T_LEN - 1;
            xb[p] = *(const u32x4*)(xpu + (size_t)tn * 256);

            LDS_BARRIER();
        }
    }
}

// -------------------------------------------------------------------------
// Kernel 2: out[b,t,:] = relu(W2 . h_{t+1} + b2), K=16 MFMA.
// h fragments read verbatim (C-frag == B-frag for 16x16x16).
// Grid 2048 = g*512 + tc, block 64, 8 t per block.
// -------------------------------------------------------------------------
__global__ __launch_bounds__(64, 2)
void out_kernel(const uint32_t* __restrict__ hg, const float* __restrict__ W2,
                const float* __restrict__ b2, float* __restrict__ out) {
    const int bid = blockIdx.x;
    const int g   = bid >> 9;
    const int tc  = bid & 511;
    const int l   = threadIdx.x;
    const int c   = l & 15, u = l >> 4;

    f16x4 wa[8][8];
#pragma unroll
    for (int m = 0; m < 8; ++m) {
        const float* wr = W2 + (16 * m + c) * 128 + 4 * u;
#pragma unroll
        for (int s = 0; s < 8; ++s)
            wa[m][s] = cvt_f16x4(*(const f32x4*)(wr + 16 * s));
    }
    f32x4 bi[8];
#pragma unroll
    for (int m = 0; m < 8; ++m) bi[m] = *(const f32x4*)(b2 + 16 * m + 4 * u);

    const int t0 = tc * 8;
    float* op0 = out + (size_t)(16 * g + c) * T_LEN * NHID + 4 * u;
#pragma unroll 1
    for (int tt = 0; tt < 8; ++tt) {
        const int t = t0 + tt;
        f16x4 hb[8];
#pragma unroll
        for (int s = 0; s < 8; ++s) {
            const uint32_t* hp = hg + (size_t)((s >> 1) * 4 + g) * T_LEN * 256
                               + (size_t)t * 256 + 4 * l + (s & 1) * 2;
            hb[s] = __builtin_bit_cast(f16x4, *(const u32x2*)hp);
        }
        f32x4 acc[8];
#pragma unroll
        for (int m = 0; m < 8; ++m) {
            f32x4 a = bi[m];
#pragma unroll
            for (int s = 0; s < 8; ++s) a = MFMA16(wa[m][s], hb[s], a);
            acc[m] = relu4(a);
        }
        float* op = op0 + (size_t)t * NHID;
#pragma unroll
        for (int m = 0; m < 8; ++m) *(f32x4*)(op + 16 * m) = acc[m];
    }
}

// -------------------------------------------------------------------------
extern "C" void kernel_launch(void* const* d_in, const int* in_sizes, int n_in,
                              void* d_out, int out_size, void* d_ws, size_t ws_size,
                              hipStream_t stream) {
    const float* input = (const float*)d_in[0];  // (64, 4096, 128) f32
    const float* W1    = (const float*)d_in[1];  // (128, 256) f32
    const float* b1    = (const float*)d_in[2];  // (128,) f32
    const float* W2    = (const float*)d_in[3];  // (128, 128) f32
    const float* b2    = (const float*)d_in[4];  // (128,) f32
    float*    out = (float*)d_out;
    uint32_t* xpb = (uint32_t*)d_out;            // xp scratch: first 64 MiB of
                                                 // d_out, fully consumed by rec
                                                 // before out_kernel overwrites
    uint32_t* hgb = (uint32_t*)d_ws;             // h stream: 64 MiB in d_ws

    xproj_kernel<<<1024, 64, 0, stream>>>(input, W1, b1, xpb);
    rec_kernel  <<<4,   256, 0, stream>>>(xpb, W1, hgb);
    out_kernel  <<<2048, 64, 0, stream>>>(hgb, W2, b2, out);
}